// Round 11
// baseline (181.434 us; speedup 1.0000x reference)
//
#include <hip/hip_runtime.h>

// Problem constants
#define B_   4
#define C_   64
#define H_   192
#define W_   640
#define D_   96     // disparities
#define TWB  64     // w1 columns per block
#define NDL  7      // 16-wide delta tiles covering d in [0,96)
#define HW_  (H_ * W_)
#define NWG  7680   // (W/TWB) * B * H = 8 * 960

typedef __attribute__((ext_vector_type(8))) short short8;
typedef __attribute__((ext_vector_type(4))) float float4v;
typedef __attribute__((ext_vector_type(4))) unsigned int uint4v;

// bank swizzle: spreads k bits into the 8x16B slot index of a 128B row
#define SWZ(x) ((((x) ^ ((x) >> 3)) & 7) << 3)

// packed f32x2 -> bf16x2 (single HW instruction, RTNE)
__device__ inline unsigned int pk2(float lo, float hi) {
    unsigned int r;
    asm("v_cvt_pk_bf16_f32 %0, %1, %2" : "=v"(r) : "v"(lo), "v"(hi));
    return r;
}

// out[b,0,d,h,w] = sum_c L[b,c,h,w] * R[b,c,h,(w - d*s) mod W] = G[w][w - s*d]
__global__ __launch_bounds__(256, 6)
void cost_volume_mfma(const float* __restrict__ Lp,
                      const float* __restrict__ Rp,
                      const int* __restrict__ dirp,
                      float* __restrict__ out)
{
    const int s = dirp[0];   // +1 or -1, uniform across grid

    // ONLY LDS: Rb [160 k][64 c] bf16, swizzled — 20 KB
    __shared__ unsigned int Rw[5120];
    const unsigned short* Rb = (const unsigned short*)Rw;

    // XCD-chunked bijective swizzle: NWG = 7680 = 8 * 960
    const int orig = blockIdx.x;
    const int nid  = (orig & 7) * (NWG / 8) + (orig >> 3);
    const int bh   = nid / 10;
    const int slab = nid - bh * 10;
    const int b  = bh / H_;
    const int h  = bh - b * H_;
    const int w0 = slab * TWB;
    const int rbase = (s == 1) ? (w0 - 96) : w0;    // global col of Rb k=0
    const int rbias = (s == 1) ? 96 : 0;            // B-frag tile bias

    const int tid  = threadIdx.x;
    const int lane = tid & 63;
    const int wv   = tid >> 6;
    const int n15  = lane & 15;
    const int lg   = lane >> 4;

    const float* Lrow = Lp + ((size_t)b * C_ * H_ + h) * W_;
    const float* Rrow = Rp + ((size_t)b * C_ * H_ + h) * W_;

    // ---- stage R only: float4 loads, convert, swizzled ds_write ----
    const int k8 = tid & 7;           // k4 low bits (coalescing)
    const int cR = (tid >> 3) * 2;    // channel pair
    const float* pc = Rrow + (size_t)cR * HW_;
#pragma unroll
    for (int u0 = 0; u0 < 5; ++u0) {
        int col = rbase + 4 * (k8 + 8 * u0);   // float4 never straddles wrap
        if (col < 0)   col += W_;
        if (col >= W_) col -= W_;
        const float4v a = *(const float4v*)(pc + col);
        const float4v q = *(const float4v*)(pc + HW_ + col);
#pragma unroll
        for (int j = 0; j < 4; ++j) {
            const int k = 4 * (k8 + 8 * u0) + j;
            Rw[k * 32 + ((cR ^ SWZ(k)) >> 1)] = pk2(a[j], q[j]);
        }
    }

    // ---- A-frag direct from global: L[w1][c], c = lg*8 + j + 32q ----
    // each (w1,c) read by exactly one lane; per instr: 4 x 64B segments
    const int w1g = w0 + 16 * wv + n15;
    short8 afrag[2];
#pragma unroll
    for (int q = 0; q < 2; ++q) {
        const float* pl = Lrow + (size_t)(lg * 8 + 32 * q) * HW_ + w1g;
        uint4v aw;
        aw[0] = pk2(pl[0 * HW_], pl[1 * HW_]);
        aw[1] = pk2(pl[2 * HW_], pl[3 * HW_]);
        aw[2] = pk2(pl[4 * HW_], pl[5 * HW_]);
        aw[3] = pk2(pl[6 * HW_], pl[7 * HW_]);
        afrag[q] = __builtin_bit_cast(short8, aw);
    }

    __syncthreads();   // Rb visible — the ONLY barrier

    // ---- MFMA: wave wv owns w1 tile [w0+16wv, +16), 7 delta tiles x K=64 ----
    float4v acc[NDL];
#pragma unroll
    for (int dl = 0; dl < NDL; ++dl) acc[dl] = (float4v)0.f;

#pragma unroll
    for (int dl = 0; dl < NDL; ++dl) {
        const int k = rbias + 16 * wv - s * 16 * dl + n15;   // 0..159
#pragma unroll
        for (int q = 0; q < 2; ++q) {
            const int c = lg * 8 + 32 * q;
            const short8 bfrag = *(const short8*)&Rb[k * 64 + (c ^ SWZ(k))];
            acc[dl] = __builtin_amdgcn_mfma_f32_16x16x32_bf16(afrag[q], bfrag, acc[dl], 0, 0, 0);
        }
    }

    // ---- direct predicated stores from accumulators ----
    // acc[dl][r] = G[w1 = w0+16wv+m][.], m = lg*4+r; d = 16dl + s*(m-n15)
    // block covers all (d, w0..w0+63) -> L2 merges the 4B stores into full lines
#pragma unroll
    for (int dl = 0; dl < NDL; ++dl) {
#pragma unroll
        for (int r = 0; r < 4; ++r) {
            const int m = lg * 4 + r;
            const int d = 16 * dl + s * (m - n15);
            if (0 <= d && d < D_)
                out[((size_t)(b * D_ + d) * H_ + h) * W_ + w0 + 16 * wv + m] = acc[dl][r];
        }
    }
}

extern "C" void kernel_launch(void* const* d_in, const int* in_sizes, int n_in,
                              void* d_out, int out_size, void* d_ws, size_t ws_size,
                              hipStream_t stream)
{
    const float* un_l = (const float*)d_in[0];
    const float* un_r = (const float*)d_in[1];
    const int*   dirp = (const int*)d_in[2];
    float* out = (float*)d_out;

    dim3 grid(NWG);    // 7680
    dim3 block(256);

    // single kernel, runtime-uniform direction
    cost_volume_mfma<<<grid, block, 0, stream>>>(un_l, un_r, dirp, out);
}

// Round 12
// 108.175 us; speedup vs baseline: 1.6772x; 1.6772x over previous
//
#include <hip/hip_runtime.h>

// Problem constants
#define B_   4
#define C_   64
#define H_   192
#define W_   640
#define D_   96     // disparities
#define TWB  64     // w1 columns per slab
#define NDL  7      // 16-wide delta tiles covering d in [0,96)
#define HW_  (H_ * W_)
#define GP   97     // Gs pitch: [w_local][d], odd -> bank = (w+d)%32, <=2-way
#define NWG  (B_ * H_)   // 768 = 8 * 96, one block per (b,h) row

typedef __attribute__((ext_vector_type(8))) short short8;
typedef __attribute__((ext_vector_type(4))) float float4v;

// bank swizzle: spreads row bits into the 8x16B slot index of a 128B row
#define SWZ(x) ((((x) ^ ((x) >> 3)) & 7) << 3)

// packed f32x2 -> bf16x2 (single HW instruction, RTNE)
__device__ inline unsigned int pk2(float lo, float hi) {
    unsigned int r;
    asm("v_cvt_pk_bf16_f32 %0, %1, %2" : "=v"(r) : "v"(lo), "v"(hi));
    return r;
}

// out[b,0,d,h,w] = sum_c L[b,c,h,w] * R[b,c,h,(w - d*s) mod W] = G[w][w - s*d]
__global__ __launch_bounds__(256)
void cost_volume_mfma(const float* __restrict__ Lp,
                      const float* __restrict__ Rp,
                      const int* __restrict__ dirp,
                      float* __restrict__ out)
{
    const int s = dirp[0];   // +1 or -1, uniform across grid

    // 28672 B union:
    //   staging: Lb [64][64] u16 @ byte 0, Rb [160][64] u16 @ byte 8192
    //   then reused as Gs [64 w][GP=97 d] f32 (24832 B)
    __shared__ unsigned int smem[7168];
    unsigned int* Lw = smem;
    unsigned int* Rw = smem + 2048;                 // byte 8192
    const unsigned short* Lb = (const unsigned short*)smem;         // byte 0
    const unsigned short* Rb = (const unsigned short*)smem + 4096;  // byte 8192
    float* Gs = (float*)smem;

    // one block per (b,h); XCD-chunked bijective swizzle: 768 = 8 * 96
    const int orig = blockIdx.x;
    const int nid  = (orig & 7) * (NWG / 8) + (orig >> 3);
    const int b = nid / H_;
    const int h = nid - b * H_;

    const int tid  = threadIdx.x;
    const int lane = tid & 63;
    const int wv   = tid >> 6;
    const int n15  = lane & 15;
    const int lg   = lane >> 4;

    const float* Lrow = Lp + ((size_t)b * C_ * H_ + h) * W_;
    const float* Rrow = Rp + ((size_t)b * C_ * H_ + h) * W_;

    const int w4 = tid & 15;          // L-stage + epilogue w group
    const int cL = (tid >> 4) * 2;    // L channel pair (0..30)
    const int k8 = tid & 7;           // R k4 low bits
    const int cR = (tid >> 3) * 2;    // R channel pair (0..62)
    const int rbias = (s == 1) ? 96 : 0;            // B-frag tile bias

    for (int slab = 0; slab < 10; ++slab) {
        const int w0 = slab * TWB;
        const int rbase = (s == 1) ? (w0 - 96) : w0;    // global col of Rb k=0

        // ---- stage L: [64 w][64 c] bf16, swizzled ----
#pragma unroll
        for (int u0 = 0; u0 < 2; ++u0) {
            const int c = cL + 32 * u0;
            const float* p0 = Lrow + (size_t)c * HW_ + w0 + 4 * w4;
            const float4v a = *(const float4v*)p0;
            const float4v q = *(const float4v*)(p0 + HW_);
#pragma unroll
            for (int j = 0; j < 4; ++j) {
                const int w = 4 * w4 + j;
                Lw[w * 32 + ((c ^ SWZ(w)) >> 1)] = pk2(a[j], q[j]);
            }
        }
        // ---- stage R: [160 k][64 c] bf16, swizzled ----
#pragma unroll
        for (int u0 = 0; u0 < 5; ++u0) {
            int col = rbase + 4 * (k8 + 8 * u0);   // float4 never straddles wrap
            if (col < 0)   col += W_;
            if (col >= W_) col -= W_;
            const float* pc = Rrow + (size_t)cR * HW_ + col;
            const float4v a = *(const float4v*)pc;
            const float4v q = *(const float4v*)(pc + HW_);
#pragma unroll
            for (int j = 0; j < 4; ++j) {
                const int k = 4 * (k8 + 8 * u0) + j;
                Rw[k * 32 + ((cR ^ SWZ(k)) >> 1)] = pk2(a[j], q[j]);
            }
        }
        __syncthreads();   // staging visible

        // ---- MFMA: wave wv owns w1 tile [w0+16wv, +16), 7 delta tiles x K=64 ----
        short8 afrag[2];
        {
            const int w = 16 * wv + n15;
#pragma unroll
            for (int q = 0; q < 2; ++q) {
                const int c = lg * 8 + 32 * q;
                afrag[q] = *(const short8*)&Lb[w * 64 + (c ^ SWZ(w))];
            }
        }

        float4v acc[NDL];
#pragma unroll
        for (int dl = 0; dl < NDL; ++dl) acc[dl] = (float4v)0.f;

#pragma unroll
        for (int dl = 0; dl < NDL; ++dl) {
            const int k = rbias + 16 * wv - s * 16 * dl + n15;   // 0..159
#pragma unroll
            for (int q = 0; q < 2; ++q) {
                const int c = lg * 8 + 32 * q;
                const short8 bfrag = *(const short8*)&Rb[k * 64 + (c ^ SWZ(k))];
                acc[dl] = __builtin_amdgcn_mfma_f32_16x16x32_bf16(afrag[q], bfrag, acc[dl], 0, 0, 0);
            }
        }
        __syncthreads();   // staging reads done; safe to overwrite with Gs

        // ---- scatter into Gs[w_local][d] (pitch 97, <=2-way banks) ----
        // D layout (16x16x32): n = lane&15 (w2), m = (lane>>4)*4 + reg (w1)
#pragma unroll
        for (int dl = 0; dl < NDL; ++dl) {
#pragma unroll
            for (int r = 0; r < 4; ++r) {
                const int m = lg * 4 + r;
                const int d = 16 * dl + s * (m - n15);
                if (0 <= d && d < D_)
                    Gs[(16 * wv + m) * GP + d] = acc[dl][r];
            }
        }
        __syncthreads();   // Gs complete

        // ---- epilogue: scalar LDS reads (bank-clean), float4 global stores ----
        const int dg = tid >> 4;
#pragma unroll
        for (int p = 0; p < 6; ++p) {
            const int d = dg + 16 * p;
            float4v v;
            v[0] = Gs[(4 * w4 + 0) * GP + d];
            v[1] = Gs[(4 * w4 + 1) * GP + d];
            v[2] = Gs[(4 * w4 + 2) * GP + d];
            v[3] = Gs[(4 * w4 + 3) * GP + d];
            *(float4v*)(out + ((size_t)(b * D_ + d) * H_ + h) * W_ + w0 + 4 * w4) = v;
        }

        if (slab < 9) __syncthreads();   // Gs reads done before next staging write
    }
}

extern "C" void kernel_launch(void* const* d_in, const int* in_sizes, int n_in,
                              void* d_out, int out_size, void* d_ws, size_t ws_size,
                              hipStream_t stream)
{
    const float* un_l = (const float*)d_in[0];
    const float* un_r = (const float*)d_in[1];
    const int*   dirp = (const int*)d_in[2];
    float* out = (float*)d_out;

    dim3 grid(NWG);    // 768 = one block per (b,h)
    dim3 block(256);

    // single kernel, runtime-uniform direction
    cost_volume_mfma<<<grid, block, 0, stream>>>(un_l, un_r, dirp, out);
}

// Round 13
// 97.037 us; speedup vs baseline: 1.8697x; 1.1148x over previous
//
#include <hip/hip_runtime.h>

// Problem constants
#define B_   4
#define C_   64
#define H_   192
#define W_   640
#define D_   96     // disparities
#define TWB  64     // w1 columns per slab
#define NDL  7      // 16-wide delta tiles covering d in [0,96)
#define HW_  (H_ * W_)
#define GP   97     // Gs pitch: [w_local][d], odd -> bank = (w+d)%32, <=2-way
#define NWG  (B_ * H_)   // 768 = 8 * 96, one block per (b,h) row

typedef __attribute__((ext_vector_type(8))) short short8;
typedef __attribute__((ext_vector_type(4))) float float4v;

// bank swizzle: spreads row bits into the 8x16B slot index of a 128B row
#define SWZ(x) ((((x) ^ ((x) >> 3)) & 7) << 3)

// packed f32x2 -> bf16x2 (single HW instruction, RTNE); volatile so it can't
// be hoisted above the s_waitcnt that lands its inputs (rule #18)
__device__ inline unsigned int pk2(float lo, float hi) {
    unsigned int r;
    asm volatile("v_cvt_pk_bf16_f32 %0, %1, %2" : "=v"(r) : "v"(lo), "v"(hi));
    return r;
}

// forced async 16B load: compiler neither serializes nor auto-waits these
#define GLOAD(dst, addr) \
    asm volatile("global_load_dwordx4 %0, %1, off" : "=v"(dst) : "v"(addr))

// issue all 14 staging loads for slab with w-origin W0 into named pf regs
#define ISSUE(W0)                                                          \
    do {                                                                   \
        const float* p0_ = Lrow + (size_t)cL * HW_ + (W0) + 4 * w4;        \
        GLOAD(pfL0, p0_);                                                  \
        GLOAD(pfL1, p0_ + HW_);                                            \
        GLOAD(pfL2, p0_ + (size_t)32 * HW_);                               \
        GLOAD(pfL3, p0_ + (size_t)33 * HW_);                               \
        const int rb_ = (s == 1) ? ((W0) - 96) : (W0);                     \
        const float* pc_ = Rrow + (size_t)cR * HW_;                        \
        int c0_ = rb_ + 4 * k8;          if (c0_ < 0) c0_ += W_; if (c0_ >= W_) c0_ -= W_; \
        int c1_ = rb_ + 4 * (k8 + 8);    if (c1_ < 0) c1_ += W_; if (c1_ >= W_) c1_ -= W_; \
        int c2_ = rb_ + 4 * (k8 + 16);   if (c2_ < 0) c2_ += W_; if (c2_ >= W_) c2_ -= W_; \
        int c3_ = rb_ + 4 * (k8 + 24);   if (c3_ < 0) c3_ += W_; if (c3_ >= W_) c3_ -= W_; \
        int c4_ = rb_ + 4 * (k8 + 32);   if (c4_ < 0) c4_ += W_; if (c4_ >= W_) c4_ -= W_; \
        GLOAD(pfR0, pc_ + c0_);  GLOAD(pfR1, pc_ + HW_ + c0_);             \
        GLOAD(pfR2, pc_ + c1_);  GLOAD(pfR3, pc_ + HW_ + c1_);             \
        GLOAD(pfR4, pc_ + c2_);  GLOAD(pfR5, pc_ + HW_ + c2_);             \
        GLOAD(pfR6, pc_ + c3_);  GLOAD(pfR7, pc_ + HW_ + c3_);             \
        GLOAD(pfR8, pc_ + c4_);  GLOAD(pfR9, pc_ + HW_ + c4_);             \
    } while (0)

// out[b,0,d,h,w] = sum_c L[b,c,h,w] * R[b,c,h,(w - d*s) mod W] = G[w][w - s*d]
__global__ __launch_bounds__(256)
void cost_volume_mfma(const float* __restrict__ Lp,
                      const float* __restrict__ Rp,
                      const int* __restrict__ dirp,
                      float* __restrict__ out)
{
    const int s = dirp[0];   // +1 or -1, uniform across grid

    // 28672 B union:
    //   staging: Lb [64][64] u16 @ byte 0, Rb [160][64] u16 @ byte 8192
    //   then reused as Gs [64 w][GP=97 d] f32 (24832 B)
    __shared__ unsigned int smem[7168];
    unsigned int* Lw = smem;
    unsigned int* Rw = smem + 2048;                 // byte 8192
    const unsigned short* Lb = (const unsigned short*)smem;         // byte 0
    const unsigned short* Rb = (const unsigned short*)smem + 4096;  // byte 8192
    float* Gs = (float*)smem;

    // one block per (b,h); XCD-chunked bijective swizzle: 768 = 8 * 96
    const int orig = blockIdx.x;
    const int nid  = (orig & 7) * (NWG / 8) + (orig >> 3);
    const int b = nid / H_;
    const int h = nid - b * H_;

    const int tid  = threadIdx.x;
    const int lane = tid & 63;
    const int wv   = tid >> 6;
    const int n15  = lane & 15;
    const int lg   = lane >> 4;

    const float* Lrow = Lp + ((size_t)b * C_ * H_ + h) * W_;
    const float* Rrow = Rp + ((size_t)b * C_ * H_ + h) * W_;

    const int w4 = tid & 15;          // L-stage + epilogue w group
    const int cL = (tid >> 4) * 2;    // L channel pair (0..30)
    const int k8 = tid & 7;           // R k4 low bits
    const int cR = (tid >> 3) * 2;    // R channel pair (0..62)
    const int rbias = (s == 1) ? 96 : 0;            // B-frag tile bias

    float4v pfL0, pfL1, pfL2, pfL3;
    float4v pfR0, pfR1, pfR2, pfR3, pfR4, pfR5, pfR6, pfR7, pfR8, pfR9;

    ISSUE(0);   // prologue: slab 0 loads in flight

    for (int slab = 0; slab < 10; ++slab) {
        const int w0 = slab * TWB;

        // ---- pf landed: convert + stage (loads were issued one phase ago) ----
        asm volatile("s_waitcnt vmcnt(0)" ::: "memory");
        __builtin_amdgcn_sched_barrier(0);
#pragma unroll
        for (int u0 = 0; u0 < 2; ++u0) {
            const int c = cL + 32 * u0;
            const float4v a = u0 ? pfL2 : pfL0;
            const float4v q = u0 ? pfL3 : pfL1;
#pragma unroll
            for (int j = 0; j < 4; ++j) {
                const int w = 4 * w4 + j;
                Lw[w * 32 + ((c ^ SWZ(w)) >> 1)] = pk2(a[j], q[j]);
            }
        }
#pragma unroll
        for (int u0 = 0; u0 < 5; ++u0) {
            const float4v a = (u0 == 0) ? pfR0 : (u0 == 1) ? pfR2 : (u0 == 2) ? pfR4 : (u0 == 3) ? pfR6 : pfR8;
            const float4v q = (u0 == 0) ? pfR1 : (u0 == 1) ? pfR3 : (u0 == 2) ? pfR5 : (u0 == 3) ? pfR7 : pfR9;
#pragma unroll
            for (int j = 0; j < 4; ++j) {
                const int k = 4 * (k8 + 8 * u0) + j;
                Rw[k * 32 + ((cR ^ SWZ(k)) >> 1)] = pk2(a[j], q[j]);
            }
        }

        // ---- issue NEXT slab's loads: in flight across all barriers below ----
        if (slab < 9) ISSUE(w0 + TWB);

        __syncthreads();   // staging visible

        // ---- MFMA: wave wv owns w1 tile [w0+16wv, +16), 7 delta tiles x K=64 ----
        short8 afrag[2];
        {
            const int w = 16 * wv + n15;
#pragma unroll
            for (int q = 0; q < 2; ++q) {
                const int c = lg * 8 + 32 * q;
                afrag[q] = *(const short8*)&Lb[w * 64 + (c ^ SWZ(w))];
            }
        }

        float4v acc[NDL];
#pragma unroll
        for (int dl = 0; dl < NDL; ++dl) acc[dl] = (float4v)0.f;

#pragma unroll
        for (int dl = 0; dl < NDL; ++dl) {
            const int k = rbias + 16 * wv - s * 16 * dl + n15;   // 0..159
#pragma unroll
            for (int q = 0; q < 2; ++q) {
                const int c = lg * 8 + 32 * q;
                const short8 bfrag = *(const short8*)&Rb[k * 64 + (c ^ SWZ(k))];
                acc[dl] = __builtin_amdgcn_mfma_f32_16x16x32_bf16(afrag[q], bfrag, acc[dl], 0, 0, 0);
            }
        }
        __syncthreads();   // staging reads done; safe to overwrite with Gs

        // ---- scatter into Gs[w_local][d] (pitch 97, <=2-way banks) ----
        // D layout (16x16x32): n = lane&15 (w2), m = (lane>>4)*4 + reg (w1)
#pragma unroll
        for (int dl = 0; dl < NDL; ++dl) {
#pragma unroll
            for (int r = 0; r < 4; ++r) {
                const int m = lg * 4 + r;
                const int d = 16 * dl + s * (m - n15);
                if (0 <= d && d < D_)
                    Gs[(16 * wv + m) * GP + d] = acc[dl][r];
            }
        }
        __syncthreads();   // Gs complete

        // ---- epilogue: scalar LDS reads (bank-clean), float4 global stores ----
        const int dg = tid >> 4;
#pragma unroll
        for (int p = 0; p < 6; ++p) {
            const int d = dg + 16 * p;
            float4v v;
            v[0] = Gs[(4 * w4 + 0) * GP + d];
            v[1] = Gs[(4 * w4 + 1) * GP + d];
            v[2] = Gs[(4 * w4 + 2) * GP + d];
            v[3] = Gs[(4 * w4 + 3) * GP + d];
            *(float4v*)(out + ((size_t)(b * D_ + d) * H_ + h) * W_ + w0 + 4 * w4) = v;
        }

        __syncthreads();   // Gs reads done before next slab's staging write
    }
}

extern "C" void kernel_launch(void* const* d_in, const int* in_sizes, int n_in,
                              void* d_out, int out_size, void* d_ws, size_t ws_size,
                              hipStream_t stream)
{
    const float* un_l = (const float*)d_in[0];
    const float* un_r = (const float*)d_in[1];
    const int*   dirp = (const int*)d_in[2];
    float* out = (float*)d_out;

    dim3 grid(NWG);    // 768 = one block per (b,h)
    dim3 block(256);

    // single kernel, runtime-uniform direction
    cost_volume_mfma<<<grid, block, 0, stream>>>(un_l, un_r, dirp, out);
}

// Round 14
// 71.026 us; speedup vs baseline: 2.5545x; 1.3662x over previous
//
#include <hip/hip_runtime.h>

// Problem constants
#define B_   4
#define C_   64
#define H_   192
#define W_   640
#define D_   96     // disparities
#define TWB  64     // w1 columns per block
#define NDL  7      // 16-wide delta tiles covering d in [0,96)
#define HW_  (H_ * W_)
#define GP   97     // Gs pitch: [w_local][d], odd -> bank = (w+d)%32, <=2-way
#define NWG  7680   // (W/TWB) * B * H = 8 * 960

typedef __attribute__((ext_vector_type(8))) short short8;
typedef __attribute__((ext_vector_type(4))) float float4v;

// bank swizzle: spreads row bits into the 8x16B slot index of a 128B row
#define SWZ(x) ((((x) ^ ((x) >> 3)) & 7) << 3)

// packed f32x2 -> bf16x2 (single HW instruction, RTNE)
__device__ inline unsigned int pk2(float lo, float hi) {
    unsigned int r;
    asm("v_cvt_pk_bf16_f32 %0, %1, %2" : "=v"(r) : "v"(lo), "v"(hi));
    return r;
}

// out[b,0,d,h,w] = sum_c L[b,c,h,w] * R[b,c,h,(w - d*s) mod W] = G[w][w - s*d]
__global__ __launch_bounds__(256)
void cost_volume_mfma(const float* __restrict__ Lp,
                      const float* __restrict__ Rp,
                      const int* __restrict__ dirp,
                      float* __restrict__ out)
{
    const int s = dirp[0];   // +1 or -1, uniform across grid

    // 28672 B union:
    //   staging: Lb [64][64] u16 @ byte 0, Rb [160][64] u16 @ byte 8192
    //   then reused as Gs [64 w][GP=97 d] f32 (24832 B)
    __shared__ unsigned int smem[7168];
    unsigned int* Lw = smem;
    unsigned int* Rw = smem + 2048;                 // byte 8192
    const unsigned short* Lb = (const unsigned short*)smem;         // byte 0
    const unsigned short* Rb = (const unsigned short*)smem + 4096;  // byte 8192
    float* Gs = (float*)smem;

    // XCD-chunked bijective swizzle: NWG = 7680 = 8 * 960
    const int orig = blockIdx.x;
    const int nid  = (orig & 7) * (NWG / 8) + (orig >> 3);
    const int bh   = nid / 10;
    const int slab = nid - bh * 10;
    const int b  = bh / H_;
    const int h  = bh - b * H_;
    const int w0 = slab * TWB;
    const int rbase = (s == 1) ? (w0 - 96) : w0;    // global col of Rb k=0
    const int rbias = (s == 1) ? 96 : 0;            // B-frag tile bias

    const int tid = threadIdx.x;
    const float* Lrow = Lp + ((size_t)b * C_ * H_ + h) * W_;
    const float* Rrow = Rp + ((size_t)b * C_ * H_ + h) * W_;

    const int w4 = tid & 15;          // L-stage + epilogue w group
    const int cL = (tid >> 4) * 2;    // L channel pair (0..30)
    const int k8 = tid & 7;           // R k4 low bits
    const int cR = (tid >> 3) * 2;    // R channel pair (0..62)

    // ---- issue ALL 14 stage loads first (MLP), statically-indexed regs ----
    float4 pf[14];
    {
        const float* p0 = Lrow + (size_t)cL * HW_ + w0 + 4 * w4;
        pf[0] = *(const float4*)(p0);
        pf[1] = *(const float4*)(p0 + HW_);
        pf[2] = *(const float4*)(p0 + (size_t)32 * HW_);
        pf[3] = *(const float4*)(p0 + (size_t)33 * HW_);
        const float* pc = Rrow + (size_t)cR * HW_;
#pragma unroll
        for (int u0 = 0; u0 < 5; ++u0) {
            int col = rbase + 4 * (k8 + 8 * u0);   // float4 never straddles wrap
            if (col < 0)   col += W_;
            if (col >= W_) col -= W_;
            pf[4 + 2 * u0] = *(const float4*)(pc + col);
            pf[5 + 2 * u0] = *(const float4*)(pc + HW_ + col);
        }
    }
    __builtin_amdgcn_sched_barrier(0);   // keep loads issued above the converts

    // ---- convert + LDS staging writes ----
#pragma unroll
    for (int u0 = 0; u0 < 2; ++u0) {
        const int c = cL + 32 * u0;
        const float4 a = pf[2 * u0], q = pf[2 * u0 + 1];
        const float av[4] = {a.x, a.y, a.z, a.w};
        const float qv[4] = {q.x, q.y, q.z, q.w};
#pragma unroll
        for (int j = 0; j < 4; ++j) {
            const int w = 4 * w4 + j;
            Lw[w * 32 + ((c ^ SWZ(w)) >> 1)] = pk2(av[j], qv[j]);
        }
    }
#pragma unroll
    for (int u0 = 0; u0 < 5; ++u0) {
        const float4 a = pf[4 + 2 * u0], q = pf[5 + 2 * u0];
        const float av[4] = {a.x, a.y, a.z, a.w};
        const float qv[4] = {q.x, q.y, q.z, q.w};
#pragma unroll
        for (int j = 0; j < 4; ++j) {
            const int k = 4 * (k8 + 8 * u0) + j;
            Rw[k * 32 + ((cR ^ SWZ(k)) >> 1)] = pk2(av[j], qv[j]);
        }
    }
    __syncthreads();   // staging visible

    // ---- MFMA: wave wv owns w1 tile [w0+16wv, +16), 7 delta tiles x K=64 ----
    const int lane = tid & 63;
    const int wv   = tid >> 6;
    const int n15  = lane & 15;
    const int lg   = lane >> 4;

    short8 afrag[2];
    {
        const int w = 16 * wv + n15;
#pragma unroll
        for (int q = 0; q < 2; ++q) {
            const int c = lg * 8 + 32 * q;
            afrag[q] = *(const short8*)&Lb[w * 64 + (c ^ SWZ(w))];
        }
    }

    float4v acc[NDL];
#pragma unroll
    for (int dl = 0; dl < NDL; ++dl) acc[dl] = (float4v)0.f;

#pragma unroll
    for (int dl = 0; dl < NDL; ++dl) {
        const int k = rbias + 16 * wv - s * 16 * dl + n15;   // 0..159
#pragma unroll
        for (int q = 0; q < 2; ++q) {
            const int c = lg * 8 + 32 * q;
            const short8 bfrag = *(const short8*)&Rb[k * 64 + (c ^ SWZ(k))];
            acc[dl] = __builtin_amdgcn_mfma_f32_16x16x32_bf16(afrag[q], bfrag, acc[dl], 0, 0, 0);
        }
    }
    __syncthreads();   // staging reads done; safe to overwrite with Gs

    // ---- scatter into Gs[w_local][d] (pitch 97, odd -> conflict-free) ----
    // D layout (16x16x32): n = lane&15 (w2), m = (lane>>4)*4 + reg (w1)
#pragma unroll
    for (int dl = 0; dl < NDL; ++dl) {
#pragma unroll
        for (int r = 0; r < 4; ++r) {
            const int m = lg * 4 + r;
            const int d = 16 * dl + s * (m - n15);
            if (0 <= d && d < D_)
                Gs[(16 * wv + m) * GP + d] = acc[dl][r];
        }
    }
    __syncthreads();   // Gs complete

    // ---- epilogue: scalar LDS reads (bank-clean), NON-TEMPORAL float4 stores
    // output lines are written once, never re-read: keep them out of L2/L3 so
    // the 252 MB input set stays resident instead (write-allocate was the
    // suspected hidden 184 MB of HBM fill reads)
    const int dg = tid >> 4;
#pragma unroll
    for (int p = 0; p < 6; ++p) {
        const int d = dg + 16 * p;
        float4v v;
        v[0] = Gs[(4 * w4 + 0) * GP + d];
        v[1] = Gs[(4 * w4 + 1) * GP + d];
        v[2] = Gs[(4 * w4 + 2) * GP + d];
        v[3] = Gs[(4 * w4 + 3) * GP + d];
        __builtin_nontemporal_store(
            v, (float4v*)(out + ((size_t)(b * D_ + d) * H_ + h) * W_ + w0 + 4 * w4));
    }
}

extern "C" void kernel_launch(void* const* d_in, const int* in_sizes, int n_in,
                              void* d_out, int out_size, void* d_ws, size_t ws_size,
                              hipStream_t stream)
{
    const float* un_l = (const float*)d_in[0];
    const float* un_r = (const float*)d_in[1];
    const int*   dirp = (const int*)d_in[2];
    float* out = (float*)d_out;

    dim3 grid(NWG);    // 7680
    dim3 block(256);

    // single kernel, runtime-uniform direction
    cost_volume_mfma<<<grid, block, 0, stream>>>(un_l, un_r, dirp, out);
}